// Round 1
// baseline (3005.272 us; speedup 1.0000x reference)
//
#include <hip/hip_runtime.h>

#define N_NODES 100000
#define IN_CH 128
#define HID_CH 256
#define OUT_CH 128
#define N_EDGES 1600000

// ---------------------------------------------------------------------------
// Kernel 1: scatter-add aggregation.  aggr[dst] += x[src]
// One thread handles one edge x 4 channels (float4 gather, 4 atomicAdds).
// ---------------------------------------------------------------------------
__global__ __launch_bounds__(256) void scatter_kernel(
    const float* __restrict__ x,
    const int* __restrict__ src,
    const int* __restrict__ dst,
    float* __restrict__ aggr) {
    int idx = blockIdx.x * 256 + threadIdx.x;   // < N_EDGES*32 = 51.2M
    int e  = idx >> 5;
    int c4 = (idx & 31) << 2;
    int s = src[e];
    int d = dst[e];
    const float4 v = *reinterpret_cast<const float4*>(x + (size_t)s * IN_CH + c4);
    float* base = aggr + (size_t)d * IN_CH + c4;
    atomicAdd(base + 0, v.x);
    atomicAdd(base + 1, v.y);
    atomicAdd(base + 2, v.z);
    atomicAdd(base + 3, v.w);
}

// ---------------------------------------------------------------------------
// Kernel 2: h1 = relu(((1+eps)*x + aggr) @ W1 + b1)     [N,128]@[128,256]
// Block: 256 threads, 8 rows/block. Thread t owns column c=t for all 8 rows.
// ---------------------------------------------------------------------------
__global__ __launch_bounds__(256) void gemm1_kernel(
    const float* __restrict__ x,
    const float* __restrict__ aggr,
    const float* __restrict__ eps_p,
    const float* __restrict__ W1,
    const float* __restrict__ b1,
    float* __restrict__ h1) {
    __shared__ float hs[8 * IN_CH];   // 4 KB
    const int row0 = blockIdx.x * 8;
    const int t = threadIdx.x;
    const float scale = 1.0f + eps_p[0];

    // stage fused input tile: 1024 floats, 4 per thread
    {
        const int off = t * 4;
        const size_t g = (size_t)row0 * IN_CH + off;
        float4 xv = *reinterpret_cast<const float4*>(x + g);
        float4 av = *reinterpret_cast<const float4*>(aggr + g);
        float4 h;
        h.x = scale * xv.x + av.x;
        h.y = scale * xv.y + av.y;
        h.z = scale * xv.z + av.z;
        h.w = scale * xv.w + av.w;
        *reinterpret_cast<float4*>(hs + off) = h;
    }
    __syncthreads();

    const int c = t;                  // output column 0..255
    float acc[8];
    #pragma unroll
    for (int r = 0; r < 8; ++r) acc[r] = 0.0f;

    #pragma unroll 4
    for (int k = 0; k < IN_CH; ++k) {
        const float w = W1[k * HID_CH + c];     // coalesced
        #pragma unroll
        for (int r = 0; r < 8; ++r)
            acc[r] += hs[r * IN_CH + k] * w;    // LDS broadcast
    }

    const float bb = b1[c];
    #pragma unroll
    for (int r = 0; r < 8; ++r) {
        float v = acc[r] + bb;
        v = v > 0.0f ? v : 0.0f;
        h1[(size_t)(row0 + r) * HID_CH + c] = v;
    }
}

// ---------------------------------------------------------------------------
// Kernel 3: out = relu(h1 @ W2 + b2)                   [N,256]@[256,128]
// Block: 256 threads, 8 rows/block. Thread t: col c=t&127, rows (t>>7)*4..+3.
// ---------------------------------------------------------------------------
__global__ __launch_bounds__(256) void gemm2_kernel(
    const float* __restrict__ h1,
    const float* __restrict__ W2,
    const float* __restrict__ b2,
    float* __restrict__ out) {
    __shared__ float hs[8 * HID_CH];  // 8 KB
    const int row0 = blockIdx.x * 8;
    const int t = threadIdx.x;

    // stage 2048 floats, 8 per thread
    {
        const int off = t * 8;
        const size_t g = (size_t)row0 * HID_CH + off;
        float4 a = *reinterpret_cast<const float4*>(h1 + g);
        float4 b = *reinterpret_cast<const float4*>(h1 + g + 4);
        *reinterpret_cast<float4*>(hs + off)     = a;
        *reinterpret_cast<float4*>(hs + off + 4) = b;
    }
    __syncthreads();

    const int c  = t & 127;
    const int rh = t >> 7;            // uniform per wave
    float acc[4] = {0.0f, 0.0f, 0.0f, 0.0f};

    #pragma unroll 4
    for (int k = 0; k < HID_CH; ++k) {
        const float w = W2[k * OUT_CH + c];     // coalesced
        #pragma unroll
        for (int j = 0; j < 4; ++j)
            acc[j] += hs[(rh * 4 + j) * HID_CH + k] * w;  // LDS broadcast
    }

    const float bb = b2[c];
    #pragma unroll
    for (int j = 0; j < 4; ++j) {
        float v = acc[j] + bb;
        v = v > 0.0f ? v : 0.0f;
        out[(size_t)(row0 + rh * 4 + j) * OUT_CH + c] = v;
    }
}

// ---------------------------------------------------------------------------
// Kernel 4: in-place log_softmax over 128 channels. One wave per row.
// ---------------------------------------------------------------------------
__global__ __launch_bounds__(256) void lsm_kernel(float* __restrict__ out) {
    const int row  = blockIdx.x * 4 + (threadIdx.x >> 6);
    const int lane = threadIdx.x & 63;
    float* p = out + (size_t)row * OUT_CH;
    const float v0 = p[lane];
    const float v1 = p[lane + 64];
    float m = fmaxf(v0, v1);
    #pragma unroll
    for (int o = 32; o > 0; o >>= 1) m = fmaxf(m, __shfl_xor(m, o));
    float s = expf(v0 - m) + expf(v1 - m);
    #pragma unroll
    for (int o = 32; o > 0; o >>= 1) s += __shfl_xor(s, o);
    const float l = m + logf(s);
    p[lane]      = v0 - l;
    p[lane + 64] = v1 - l;
}

extern "C" void kernel_launch(void* const* d_in, const int* in_sizes, int n_in,
                              void* d_out, int out_size, void* d_ws, size_t ws_size,
                              hipStream_t stream) {
    const float* x    = (const float*)d_in[0];
    const int*   ei   = (const int*)d_in[1];
    const float* W1   = (const float*)d_in[2];
    const float* b1   = (const float*)d_in[3];
    const float* W2   = (const float*)d_in[4];
    const float* b2   = (const float*)d_in[5];
    const float* eps  = (const float*)d_in[6];
    float* out = (float*)d_out;

    float* aggr = (float*)d_ws;                          // 100000*128 f32 = 51.2 MB
    float* h1   = aggr + (size_t)N_NODES * IN_CH;        // 100000*256 f32 = 102.4 MB

    const int* src = ei;
    const int* dst = ei + N_EDGES;

    hipMemsetAsync(aggr, 0, (size_t)N_NODES * IN_CH * sizeof(float), stream);

    scatter_kernel<<<(N_EDGES * 32) / 256, 256, 0, stream>>>(x, src, dst, aggr);
    gemm1_kernel<<<N_NODES / 8, 256, 0, stream>>>(x, aggr, eps, W1, b1, h1);
    gemm2_kernel<<<N_NODES / 8, 256, 0, stream>>>(h1, W2, b2, out);
    lsm_kernel<<<N_NODES / 4, 256, 0, stream>>>(out);
}

// Round 2
// 633.962 us; speedup vs baseline: 4.7405x; 4.7405x over previous
//
#include <hip/hip_runtime.h>

#define N_NODES 100000
#define IN_CH 128
#define HID_CH 256
#define OUT_CH 128
#define N_EDGES 1600000

#define SCAN_CHUNK 1024
#define N_SCAN_BLOCKS ((N_NODES + SCAN_CHUNK - 1) / SCAN_CHUNK)   // 98

// ---------------------------------------------------------------------------
// CSR build, step 1: degree histogram.  deg[dst]++ per edge.
// ---------------------------------------------------------------------------
__global__ __launch_bounds__(256) void hist_kernel(
    const int* __restrict__ dst, int* __restrict__ deg) {
    int e = blockIdx.x * 256 + threadIdx.x;
    if (e < N_EDGES) atomicAdd(&deg[dst[e]], 1);
}

// ---------------------------------------------------------------------------
// CSR build, step 2a: per-chunk exclusive scan (1024 elems/block, in-place
// into offs) + chunk totals.
// ---------------------------------------------------------------------------
__global__ __launch_bounds__(256) void scan1_kernel(
    const int* __restrict__ deg, int* __restrict__ offs,
    int* __restrict__ blockSums) {
    __shared__ int ts[256];
    const int b = blockIdx.x;
    const int t = threadIdx.x;
    const int base = b * SCAN_CHUNK + t * 4;
    int v0 = 0, v1 = 0, v2 = 0, v3 = 0;
    if (base + 0 < N_NODES) v0 = deg[base + 0];
    if (base + 1 < N_NODES) v1 = deg[base + 1];
    if (base + 2 < N_NODES) v2 = deg[base + 2];
    if (base + 3 < N_NODES) v3 = deg[base + 3];
    const int s = v0 + v1 + v2 + v3;
    ts[t] = s;
    __syncthreads();
    #pragma unroll
    for (int o = 1; o < 256; o <<= 1) {
        int add = (t >= o) ? ts[t - o] : 0;
        __syncthreads();
        ts[t] += add;
        __syncthreads();
    }
    const int excl = ts[t] - s;
    if (t == 255) blockSums[b] = ts[255];
    if (base + 0 < N_NODES) offs[base + 0] = excl;
    if (base + 1 < N_NODES) offs[base + 1] = excl + v0;
    if (base + 2 < N_NODES) offs[base + 2] = excl + v0 + v1;
    if (base + 3 < N_NODES) offs[base + 3] = excl + v0 + v1 + v2;
}

// ---------------------------------------------------------------------------
// CSR build, step 2b: exclusive scan of the 98 chunk totals (single block).
// ---------------------------------------------------------------------------
__global__ __launch_bounds__(128) void scan2_kernel(int* __restrict__ blockSums) {
    __shared__ int ts[128];
    const int t = threadIdx.x;
    const int v = (t < N_SCAN_BLOCKS) ? blockSums[t] : 0;
    ts[t] = v;
    __syncthreads();
    #pragma unroll
    for (int o = 1; o < 128; o <<= 1) {
        int add = (t >= o) ? ts[t - o] : 0;
        __syncthreads();
        ts[t] += add;
        __syncthreads();
    }
    if (t < N_SCAN_BLOCKS) blockSums[t] = ts[t] - v;   // exclusive
}

// ---------------------------------------------------------------------------
// CSR build, step 2c: add chunk offsets (in-place), init cursors, sentinel.
// ---------------------------------------------------------------------------
__global__ __launch_bounds__(256) void finalize_kernel(
    int* __restrict__ offs, const int* __restrict__ blockSums,
    int* __restrict__ cursor) {
    const int i = blockIdx.x * 256 + threadIdx.x;
    if (i < N_NODES) {
        const int v = offs[i] + blockSums[i >> 10];
        offs[i] = v;
        cursor[i] = v;
    }
    if (i == 0) offs[N_NODES] = N_EDGES;
}

// ---------------------------------------------------------------------------
// CSR build, step 3: bucket fill.  csr_src[pos++] = src per edge.
// ---------------------------------------------------------------------------
__global__ __launch_bounds__(256) void fill_kernel(
    const int* __restrict__ src, const int* __restrict__ dst,
    int* __restrict__ cursor, int* __restrict__ csr_src) {
    int e = blockIdx.x * 256 + threadIdx.x;
    if (e < N_EDGES) {
        const int p = atomicAdd(&cursor[dst[e]], 1);
        csr_src[p] = src[e];
    }
}

// ---------------------------------------------------------------------------
// Gather-aggregate: aggr[i] = sum_{j in N(i)} x[j].  8 nodes per block,
// 32 threads per node, float4 per thread (512 B coalesced row reads).
// ---------------------------------------------------------------------------
__global__ __launch_bounds__(256) void gather_kernel(
    const float* __restrict__ x,
    const int* __restrict__ offs,
    const int* __restrict__ csr_src,
    float* __restrict__ aggr) {
    const int node = blockIdx.x * 8 + (threadIdx.x >> 5);
    const int c4   = (threadIdx.x & 31) << 2;
    const int beg = offs[node];
    const int end = offs[node + 1];
    float4 acc = {0.0f, 0.0f, 0.0f, 0.0f};
    for (int e = beg; e < end; ++e) {
        const int s = csr_src[e];
        const float4 v = *reinterpret_cast<const float4*>(
            x + (size_t)s * IN_CH + c4);
        acc.x += v.x; acc.y += v.y; acc.z += v.z; acc.w += v.w;
    }
    *reinterpret_cast<float4*>(aggr + (size_t)node * IN_CH + c4) = acc;
}

// ---------------------------------------------------------------------------
// Kernel: h1 = relu(((1+eps)*x + aggr) @ W1 + b1)     [N,128]@[128,256]
// ---------------------------------------------------------------------------
__global__ __launch_bounds__(256) void gemm1_kernel(
    const float* __restrict__ x,
    const float* __restrict__ aggr,
    const float* __restrict__ eps_p,
    const float* __restrict__ W1,
    const float* __restrict__ b1,
    float* __restrict__ h1) {
    __shared__ float hs[8 * IN_CH];   // 4 KB
    const int row0 = blockIdx.x * 8;
    const int t = threadIdx.x;
    const float scale = 1.0f + eps_p[0];

    {
        const int off = t * 4;
        const size_t g = (size_t)row0 * IN_CH + off;
        float4 xv = *reinterpret_cast<const float4*>(x + g);
        float4 av = *reinterpret_cast<const float4*>(aggr + g);
        float4 h;
        h.x = scale * xv.x + av.x;
        h.y = scale * xv.y + av.y;
        h.z = scale * xv.z + av.z;
        h.w = scale * xv.w + av.w;
        *reinterpret_cast<float4*>(hs + off) = h;
    }
    __syncthreads();

    const int c = t;
    float acc[8];
    #pragma unroll
    for (int r = 0; r < 8; ++r) acc[r] = 0.0f;

    #pragma unroll 4
    for (int k = 0; k < IN_CH; ++k) {
        const float w = W1[k * HID_CH + c];
        #pragma unroll
        for (int r = 0; r < 8; ++r)
            acc[r] += hs[r * IN_CH + k] * w;
    }

    const float bb = b1[c];
    #pragma unroll
    for (int r = 0; r < 8; ++r) {
        float v = acc[r] + bb;
        v = v > 0.0f ? v : 0.0f;
        h1[(size_t)(row0 + r) * HID_CH + c] = v;
    }
}

// ---------------------------------------------------------------------------
// Kernel: out = relu(h1 @ W2 + b2)                   [N,256]@[256,128]
// ---------------------------------------------------------------------------
__global__ __launch_bounds__(256) void gemm2_kernel(
    const float* __restrict__ h1,
    const float* __restrict__ W2,
    const float* __restrict__ b2,
    float* __restrict__ out) {
    __shared__ float hs[8 * HID_CH];  // 8 KB
    const int row0 = blockIdx.x * 8;
    const int t = threadIdx.x;

    {
        const int off = t * 8;
        const size_t g = (size_t)row0 * HID_CH + off;
        float4 a = *reinterpret_cast<const float4*>(h1 + g);
        float4 b = *reinterpret_cast<const float4*>(h1 + g + 4);
        *reinterpret_cast<float4*>(hs + off)     = a;
        *reinterpret_cast<float4*>(hs + off + 4) = b;
    }
    __syncthreads();

    const int c  = t & 127;
    const int rh = t >> 7;
    float acc[4] = {0.0f, 0.0f, 0.0f, 0.0f};

    #pragma unroll 4
    for (int k = 0; k < HID_CH; ++k) {
        const float w = W2[k * OUT_CH + c];
        #pragma unroll
        for (int j = 0; j < 4; ++j)
            acc[j] += hs[(rh * 4 + j) * HID_CH + k] * w;
    }

    const float bb = b2[c];
    #pragma unroll
    for (int j = 0; j < 4; ++j) {
        float v = acc[j] + bb;
        v = v > 0.0f ? v : 0.0f;
        out[(size_t)(row0 + rh * 4 + j) * OUT_CH + c] = v;
    }
}

// ---------------------------------------------------------------------------
// In-place log_softmax over 128 channels. One wave per row.
// ---------------------------------------------------------------------------
__global__ __launch_bounds__(256) void lsm_kernel(float* __restrict__ out) {
    const int row  = blockIdx.x * 4 + (threadIdx.x >> 6);
    const int lane = threadIdx.x & 63;
    float* p = out + (size_t)row * OUT_CH;
    const float v0 = p[lane];
    const float v1 = p[lane + 64];
    float m = fmaxf(v0, v1);
    #pragma unroll
    for (int o = 32; o > 0; o >>= 1) m = fmaxf(m, __shfl_xor(m, o));
    float s = expf(v0 - m) + expf(v1 - m);
    #pragma unroll
    for (int o = 32; o > 0; o >>= 1) s += __shfl_xor(s, o);
    const float l = m + logf(s);
    p[lane]      = v0 - l;
    p[lane + 64] = v1 - l;
}

extern "C" void kernel_launch(void* const* d_in, const int* in_sizes, int n_in,
                              void* d_out, int out_size, void* d_ws, size_t ws_size,
                              hipStream_t stream) {
    const float* x    = (const float*)d_in[0];
    const int*   ei   = (const int*)d_in[1];
    const float* W1   = (const float*)d_in[2];
    const float* b1   = (const float*)d_in[3];
    const float* W2   = (const float*)d_in[4];
    const float* b2   = (const float*)d_in[5];
    const float* eps  = (const float*)d_in[6];
    float* out = (float*)d_out;

    // workspace layout
    float* aggr = (float*)d_ws;                              // 12.8M f32 (51.2 MB)
    float* h1   = aggr + (size_t)N_NODES * IN_CH;            // 25.6M f32 (102.4 MB)
    int* ibase     = (int*)(h1 + (size_t)N_NODES * HID_CH);
    int* deg       = ibase;                                  // 100000
    int* offs      = deg + N_NODES;                          // 100001
    int* cursor    = offs + N_NODES + 1;                     // 100000
    int* blockSums = cursor + N_NODES;                       // 128
    int* csr_src   = blockSums + 128;                        // 1.6M

    const int* src = ei;
    const int* dst = ei + N_EDGES;

    hipMemsetAsync(deg, 0, (size_t)N_NODES * sizeof(int), stream);

    hist_kernel<<<(N_EDGES + 255) / 256, 256, 0, stream>>>(dst, deg);
    scan1_kernel<<<N_SCAN_BLOCKS, 256, 0, stream>>>(deg, offs, blockSums);
    scan2_kernel<<<1, 128, 0, stream>>>(blockSums);
    finalize_kernel<<<(N_NODES + 255) / 256, 256, 0, stream>>>(offs, blockSums, cursor);
    fill_kernel<<<(N_EDGES + 255) / 256, 256, 0, stream>>>(src, dst, cursor, csr_src);
    gather_kernel<<<N_NODES / 8, 256, 0, stream>>>(x, offs, csr_src, aggr);

    gemm1_kernel<<<N_NODES / 8, 256, 0, stream>>>(x, aggr, eps, W1, b1, h1);
    gemm2_kernel<<<N_NODES / 8, 256, 0, stream>>>(h1, W2, b2, out);
    lsm_kernel<<<N_NODES / 4, 256, 0, stream>>>(out);
}

// Round 3
// 455.575 us; speedup vs baseline: 6.5967x; 1.3916x over previous
//
#include <hip/hip_runtime.h>

#define N_NODES 100000
#define IN_CH 128
#define HID_CH 256
#define OUT_CH 128
#define N_EDGES 1600000

#define SCAN_CHUNK 1024
#define N_SCAN_BLOCKS ((N_NODES + SCAN_CHUNK - 1) / SCAN_CHUNK)   // 98

typedef __attribute__((ext_vector_type(8))) short short8;
typedef __attribute__((ext_vector_type(4))) float f32x4;

// bf16 <-> f32 helpers (bit ops; finite data only)
__device__ __forceinline__ float b2f(ushort u) {
    unsigned int x = ((unsigned int)u) << 16;
    return __uint_as_float(x);
}
__device__ __forceinline__ ushort f2b(float f) {
    unsigned int u = __float_as_uint(f);
    u += 0x7FFFu + ((u >> 16) & 1u);   // round-to-nearest-even
    return (ushort)(u >> 16);
}

// ---------------------------------------------------------------------------
// Prep: x fp32 -> xb bf16 ; W1 [128][256] -> W1T bf16 [256][128] ;
//       W2 [256][128] -> W2T bf16 [128][256]
// ---------------------------------------------------------------------------
#define PREP_X_BLOCKS 6250        // 6250*2048 = 12.8M = N_NODES*IN_CH
#define PREP_W1_BLOCKS 128        // 32768 elems
#define PREP_W2_BLOCKS 128        // 32768 elems
__global__ __launch_bounds__(256) void prep_kernel(
    const float* __restrict__ x, const float* __restrict__ W1,
    const float* __restrict__ W2,
    ushort* __restrict__ xb, ushort* __restrict__ W1T,
    ushort* __restrict__ W2T) {
    const int b = blockIdx.x;
    const int t = threadIdx.x;
    if (b < PREP_X_BLOCKS) {
        const size_t i = (size_t)b * 2048 + t * 8;
        float4 a = *reinterpret_cast<const float4*>(x + i);
        float4 c = *reinterpret_cast<const float4*>(x + i + 4);
        ushort v[8] = {f2b(a.x), f2b(a.y), f2b(a.z), f2b(a.w),
                       f2b(c.x), f2b(c.y), f2b(c.z), f2b(c.w)};
        *reinterpret_cast<short8*>(xb + i) = *reinterpret_cast<short8*>(v);
    } else if (b < PREP_X_BLOCKS + PREP_W1_BLOCKS) {
        const int i = (b - PREP_X_BLOCKS) * 256 + t;     // oc*128 + k
        const int oc = i >> 7, k = i & 127;
        W1T[i] = f2b(W1[k * HID_CH + oc]);
    } else {
        const int i = (b - PREP_X_BLOCKS - PREP_W1_BLOCKS) * 256 + t; // oc*256+k
        const int oc = i >> 8, k = i & 255;
        W2T[i] = f2b(W2[k * OUT_CH + oc]);
    }
}

// ---------------------------------------------------------------------------
// CSR build
// ---------------------------------------------------------------------------
__global__ __launch_bounds__(256) void hist_kernel(
    const int* __restrict__ dst, int* __restrict__ deg) {
    int e = blockIdx.x * 256 + threadIdx.x;
    if (e < N_EDGES) atomicAdd(&deg[dst[e]], 1);
}

__global__ __launch_bounds__(256) void scan1_kernel(
    const int* __restrict__ deg, int* __restrict__ offs,
    int* __restrict__ blockSums) {
    __shared__ int ts[256];
    const int b = blockIdx.x;
    const int t = threadIdx.x;
    const int base = b * SCAN_CHUNK + t * 4;
    int v0 = 0, v1 = 0, v2 = 0, v3 = 0;
    if (base + 0 < N_NODES) v0 = deg[base + 0];
    if (base + 1 < N_NODES) v1 = deg[base + 1];
    if (base + 2 < N_NODES) v2 = deg[base + 2];
    if (base + 3 < N_NODES) v3 = deg[base + 3];
    const int s = v0 + v1 + v2 + v3;
    ts[t] = s;
    __syncthreads();
    #pragma unroll
    for (int o = 1; o < 256; o <<= 1) {
        int add = (t >= o) ? ts[t - o] : 0;
        __syncthreads();
        ts[t] += add;
        __syncthreads();
    }
    const int excl = ts[t] - s;
    if (t == 255) blockSums[b] = ts[255];
    if (base + 0 < N_NODES) offs[base + 0] = excl;
    if (base + 1 < N_NODES) offs[base + 1] = excl + v0;
    if (base + 2 < N_NODES) offs[base + 2] = excl + v0 + v1;
    if (base + 3 < N_NODES) offs[base + 3] = excl + v0 + v1 + v2;
}

__global__ __launch_bounds__(128) void scan2_kernel(int* __restrict__ blockSums) {
    __shared__ int ts[128];
    const int t = threadIdx.x;
    const int v = (t < N_SCAN_BLOCKS) ? blockSums[t] : 0;
    ts[t] = v;
    __syncthreads();
    #pragma unroll
    for (int o = 1; o < 128; o <<= 1) {
        int add = (t >= o) ? ts[t - o] : 0;
        __syncthreads();
        ts[t] += add;
        __syncthreads();
    }
    if (t < N_SCAN_BLOCKS) blockSums[t] = ts[t] - v;
}

__global__ __launch_bounds__(256) void finalize_kernel(
    int* __restrict__ offs, const int* __restrict__ blockSums,
    int* __restrict__ cursor) {
    const int i = blockIdx.x * 256 + threadIdx.x;
    if (i < N_NODES) {
        const int v = offs[i] + blockSums[i >> 10];
        offs[i] = v;
        cursor[i] = v;
    }
    if (i == 0) offs[N_NODES] = N_EDGES;
}

__global__ __launch_bounds__(256) void fill_kernel(
    const int* __restrict__ src, const int* __restrict__ dst,
    int* __restrict__ cursor, int* __restrict__ csr_src) {
    int e = blockIdx.x * 256 + threadIdx.x;
    if (e < N_EDGES) {
        const int p = atomicAdd(&cursor[dst[e]], 1);
        csr_src[p] = src[e];
    }
}

// ---------------------------------------------------------------------------
// Gather-aggregate fused with GIN self-term:
//   h_in[i] = bf16( (1+eps)*x[i] + sum_{j in N(i)} x[j] )   (fp32 accum)
// 8 nodes/block, 32 threads/node, 4 channels (8 B bf16) per thread.
// ---------------------------------------------------------------------------
__global__ __launch_bounds__(256) void gather_kernel(
    const ushort* __restrict__ xb,
    const float* __restrict__ eps_p,
    const int* __restrict__ offs,
    const int* __restrict__ csr_src,
    ushort* __restrict__ h_in) {
    const int node = blockIdx.x * 8 + (threadIdx.x >> 5);
    const int c = (threadIdx.x & 31) * 4;
    const int beg = offs[node];
    const int end = offs[node + 1];
    float a0 = 0.f, a1 = 0.f, a2 = 0.f, a3 = 0.f;
    for (int e = beg; e < end; ++e) {
        const int s = csr_src[e];
        ushort4 v = *reinterpret_cast<const ushort4*>(xb + (size_t)s * IN_CH + c);
        a0 += b2f(v.x); a1 += b2f(v.y); a2 += b2f(v.z); a3 += b2f(v.w);
    }
    const float scale = 1.0f + eps_p[0];
    ushort4 sv = *reinterpret_cast<const ushort4*>(xb + (size_t)node * IN_CH + c);
    ushort4 o;
    o.x = f2b(scale * b2f(sv.x) + a0);
    o.y = f2b(scale * b2f(sv.y) + a1);
    o.z = f2b(scale * b2f(sv.z) + a2);
    o.w = f2b(scale * b2f(sv.w) + a3);
    *reinterpret_cast<ushort4*>(h_in + (size_t)node * IN_CH + c) = o;
}

// ---------------------------------------------------------------------------
// GEMM1 (MFMA): h1 = bf16(relu(h_in @ W1 + b1))   [N,128]@[128,256] -> [N,256]
// 256 thr = 4 waves; wave w: rows [blk*64 + w*16, +16), all 256 cols.
// A frags direct from global (16B/lane); B from W1T [col][k] (L2-hot).
// ---------------------------------------------------------------------------
__global__ __launch_bounds__(256) void gemm1_mfma(
    const ushort* __restrict__ h_in,
    const ushort* __restrict__ W1T,
    const float* __restrict__ b1,
    ushort* __restrict__ h1) {
    const int w    = threadIdx.x >> 6;
    const int lane = threadIdx.x & 63;
    const int lr   = lane & 15;
    const int lk   = lane >> 4;
    const int arow = blockIdx.x * 64 + w * 16 + lr;
    const int arc  = arow < N_NODES ? arow : N_NODES - 1;

    short8 a[4];
    const ushort* ap = h_in + (size_t)arc * IN_CH + lk * 8;
    #pragma unroll
    for (int kk = 0; kk < 4; ++kk)
        a[kk] = *reinterpret_cast<const short8*>(ap + kk * 32);

    f32x4 acc[16];
    #pragma unroll
    for (int ct = 0; ct < 16; ++ct) acc[ct] = (f32x4){0.f, 0.f, 0.f, 0.f};

    #pragma unroll
    for (int ct = 0; ct < 16; ++ct) {
        const ushort* bp = W1T + (size_t)(ct * 16 + lr) * IN_CH + lk * 8;
        #pragma unroll
        for (int kk = 0; kk < 4; ++kk) {
            short8 b = *reinterpret_cast<const short8*>(bp + kk * 32);
            acc[ct] = __builtin_amdgcn_mfma_f32_16x16x32_bf16(a[kk], b, acc[ct], 0, 0, 0);
        }
    }

    const int orow0 = blockIdx.x * 64 + w * 16 + lk * 4;
    #pragma unroll
    for (int ct = 0; ct < 16; ++ct) {
        const int col = ct * 16 + lr;
        const float bb = b1[col];
        #pragma unroll
        for (int r = 0; r < 4; ++r) {
            const int orow = orow0 + r;
            if (orow < N_NODES) {
                float v = fmaxf(acc[ct][r] + bb, 0.0f);
                h1[(size_t)orow * HID_CH + col] = f2b(v);
            }
        }
    }
}

// ---------------------------------------------------------------------------
// GEMM2 (MFMA) + fused bias/relu/log_softmax:
//   out = log_softmax(relu(h1 @ W2 + b2))   [N,256]@[256,128] -> [N,128] fp32
// Row r's 128 cols live in one 16-lane group (8 frags x reg) -> shfl reduce.
// ---------------------------------------------------------------------------
__global__ __launch_bounds__(256) void gemm2_mfma(
    const ushort* __restrict__ h1,
    const ushort* __restrict__ W2T,
    const float* __restrict__ b2,
    float* __restrict__ out) {
    const int w    = threadIdx.x >> 6;
    const int lane = threadIdx.x & 63;
    const int lr   = lane & 15;
    const int lk   = lane >> 4;
    const int arow = blockIdx.x * 64 + w * 16 + lr;
    const int arc  = arow < N_NODES ? arow : N_NODES - 1;

    short8 a[8];
    const ushort* ap = h1 + (size_t)arc * HID_CH + lk * 8;
    #pragma unroll
    for (int kk = 0; kk < 8; ++kk)
        a[kk] = *reinterpret_cast<const short8*>(ap + kk * 32);

    f32x4 acc[8];
    #pragma unroll
    for (int ct = 0; ct < 8; ++ct) acc[ct] = (f32x4){0.f, 0.f, 0.f, 0.f};

    #pragma unroll
    for (int ct = 0; ct < 8; ++ct) {
        const ushort* bp = W2T + (size_t)(ct * 16 + lr) * HID_CH + lk * 8;
        #pragma unroll
        for (int kk = 0; kk < 8; ++kk) {
            short8 b = *reinterpret_cast<const short8*>(bp + kk * 32);
            acc[ct] = __builtin_amdgcn_mfma_f32_16x16x32_bf16(a[kk], b, acc[ct], 0, 0, 0);
        }
    }

    float bias[8];
    #pragma unroll
    for (int ct = 0; ct < 8; ++ct) bias[ct] = b2[ct * 16 + lr];

    const int orow0 = blockIdx.x * 64 + w * 16 + lk * 4;
    #pragma unroll
    for (int r = 0; r < 4; ++r) {
        float v[8];
        float m = -1e30f;
        #pragma unroll
        for (int ct = 0; ct < 8; ++ct) {
            v[ct] = fmaxf(acc[ct][r] + bias[ct], 0.0f);
            m = fmaxf(m, v[ct]);
        }
        #pragma unroll
        for (int o = 1; o < 16; o <<= 1) m = fmaxf(m, __shfl_xor(m, o));
        float s = 0.0f;
        #pragma unroll
        for (int ct = 0; ct < 8; ++ct) s += __expf(v[ct] - m);
        #pragma unroll
        for (int o = 1; o < 16; o <<= 1) s += __shfl_xor(s, o);
        const float lse = m + __logf(s);
        const int orow = orow0 + r;
        if (orow < N_NODES) {
            #pragma unroll
            for (int ct = 0; ct < 8; ++ct)
                out[(size_t)orow * OUT_CH + ct * 16 + lr] = v[ct] - lse;
        }
    }
}

extern "C" void kernel_launch(void* const* d_in, const int* in_sizes, int n_in,
                              void* d_out, int out_size, void* d_ws, size_t ws_size,
                              hipStream_t stream) {
    const float* x    = (const float*)d_in[0];
    const int*   ei   = (const int*)d_in[1];
    const float* W1   = (const float*)d_in[2];
    const float* b1   = (const float*)d_in[3];
    const float* W2   = (const float*)d_in[4];
    const float* b2   = (const float*)d_in[5];
    const float* eps  = (const float*)d_in[6];
    float* out = (float*)d_out;

    // workspace layout (bf16 = ushort)
    ushort* xb   = (ushort*)d_ws;                          // 12.8M
    ushort* h_in = xb + (size_t)N_NODES * IN_CH;           // 12.8M
    ushort* h1   = h_in + (size_t)N_NODES * IN_CH;         // 25.6M
    ushort* W1T  = h1 + (size_t)N_NODES * HID_CH;          // 32768
    ushort* W2T  = W1T + IN_CH * HID_CH;                   // 32768
    int* ibase     = (int*)(W2T + HID_CH * OUT_CH);
    int* deg       = ibase;                                // 100000
    int* offs      = deg + N_NODES;                        // 100001
    int* cursor    = offs + N_NODES + 1;                   // 100000
    int* blockSums = cursor + N_NODES;                     // 128
    int* csr_src   = blockSums + 128;                      // 1.6M

    const int* src = ei;
    const int* dst = ei + N_EDGES;

    hipMemsetAsync(deg, 0, (size_t)N_NODES * sizeof(int), stream);

    prep_kernel<<<PREP_X_BLOCKS + PREP_W1_BLOCKS + PREP_W2_BLOCKS, 256, 0, stream>>>(
        x, W1, W2, xb, W1T, W2T);
    hist_kernel<<<(N_EDGES + 255) / 256, 256, 0, stream>>>(dst, deg);
    scan1_kernel<<<N_SCAN_BLOCKS, 256, 0, stream>>>(deg, offs, blockSums);
    scan2_kernel<<<1, 128, 0, stream>>>(blockSums);
    finalize_kernel<<<(N_NODES + 255) / 256, 256, 0, stream>>>(offs, blockSums, cursor);
    fill_kernel<<<(N_EDGES + 255) / 256, 256, 0, stream>>>(src, dst, cursor, csr_src);
    gather_kernel<<<N_NODES / 8, 256, 0, stream>>>(xb, eps, offs, csr_src, h_in);

    gemm1_mfma<<<(N_NODES + 63) / 64, 256, 0, stream>>>(h_in, W1T, b1, h1);
    gemm2_mfma<<<(N_NODES + 63) / 64, 256, 0, stream>>>(h1, W2T, b2, out);
}